// Round 1
// baseline (930.328 us; speedup 1.0000x reference)
//
#include <hip/hip_runtime.h>
#include <cstdint>
#include <cfloat>

// ---------------------------------------------------------------------------
// SimpleVQVAEEncoder: conv(3->64,8x8,s4,p2)+relu -> conv(64->128,6x6,s3,p2)+relu
//                     -> conv(128->64,4x4,s1,p0) -> VQ argmin -> one-hot [B,512,169]
// All fp32 (no fp32 MFMA on CDNA4; one-hot output demands exact argmin => keep
// full precision). Implicit-GEMM convs: 64-pixel x OC tile per block, BK=32.
// ---------------------------------------------------------------------------

constexpr int B_   = 128;
constexpr int HW3  = 13 * 13;          // 169
constexpr int NPIXT = B_ * HW3;        // 21632 total pixels after encoder
constexpr int NEMB = 512;
constexpr int EMB  = 64;

template<int IC, int OC, int KH, int KW, int IH, int IW, int OH, int OW,
         int STRIDE, int PAD, bool RELU, bool PIXMAJOR, bool ONED, int TPY, int TPX>
__global__ __launch_bounds__(256) void conv_igemm(
    const float* __restrict__ in, const float* __restrict__ wt,
    const float* __restrict__ bias, float* __restrict__ out)
{
    constexpr int K  = IC * KH * KW;
    constexpr int BK = 32;
    constexpr int NPIX = 4;
    constexpr int NOC  = OC / 16;        // 4 (OC=64) or 8 (OC=128)
    constexpr int BSTR = OC + 4;         // pad to dodge staging-write conflicts

    __shared__ alignas(16) float As[BK][64];
    __shared__ alignas(16) float Bs[BK][BSTR];

    const int tid = threadIdx.x;
    int bx = blockIdx.x;
    int n, ty, tx;
    if (ONED) {
        constexpr int NT = (OH * OW + 63) / 64;
        n  = bx / NT;
        tx = bx - n * NT;
        ty = 0;
    } else {
        constexpr int TX = OW / TPX, TY = OH / TPY;
        n = bx / (TX * TY);
        int r = bx - n * (TX * TY);
        ty = r / TX;
        tx = r - ty * TX;
    }

    const int pg  = tid & 15;     // pixel group: 16 groups of 4 pixels
    const int og  = tid >> 4;     // oc group:   16 groups of NOC ocs
    const int p0  = pg * NPIX;
    const int oc0 = og * NOC;

    float acc[NPIX][NOC];
#pragma unroll
    for (int i = 0; i < NPIX; i++)
#pragma unroll
        for (int j = 0; j < NOC; j++) acc[i][j] = 0.f;

    for (int k0 = 0; k0 < K; k0 += BK) {
        // ---- stage A (im2col gather): BK x 64 pixels ----
#pragma unroll
        for (int i = 0; i < (BK * 64) / 256; i++) {
            int idx = i * 256 + tid;
            int p   = idx & 63;
            int kk  = idx >> 6;
            int k   = k0 + kk;
            int ic  = k / (KH * KW);
            int r   = k - ic * (KH * KW);
            int ky  = r / KW;
            int kx  = r - ky * KW;
            int oy, ox;
            if (ONED) {
                int hw = tx * 64 + p;
                if (hw >= OH * OW) hw = 0;       // dummy; masked at store
                oy = hw / OW;
                ox = hw - oy * OW;
            } else {
                oy = ty * TPY + (p >> 3);
                ox = tx * TPX + (p & 7);
            }
            int iy = oy * STRIDE - PAD + ky;
            int ix = ox * STRIDE - PAD + kx;
            float v = 0.f;
            if (iy >= 0 && iy < IH && ix >= 0 && ix < IW)
                v = in[((size_t)(n * IC + ic) * IH + iy) * IW + ix];
            As[kk][p] = v;
        }
        // ---- stage B (transpose to [kk][oc]): BK x OC ----
#pragma unroll
        for (int i = 0; i < (BK * OC) / 256; i++) {
            int idx = i * 256 + tid;
            int kk  = idx & (BK - 1);
            int oc  = idx >> 5;
            Bs[kk][oc] = wt[(size_t)oc * K + k0 + kk];
        }
        __syncthreads();

        // ---- inner outer-product: per kk: 1xA float4 + NOC/4 x B float4 ----
#pragma unroll
        for (int kk = 0; kk < BK; kk++) {
            float4 a = *(const float4*)&As[kk][p0];
            float av[4] = {a.x, a.y, a.z, a.w};
            float bv[NOC];
#pragma unroll
            for (int j = 0; j < NOC; j += 4) {
                float4 b = *(const float4*)&Bs[kk][oc0 + j];
                bv[j] = b.x; bv[j+1] = b.y; bv[j+2] = b.z; bv[j+3] = b.w;
            }
#pragma unroll
            for (int i = 0; i < NPIX; i++)
#pragma unroll
                for (int j = 0; j < NOC; j++)
                    acc[i][j] = fmaf(av[i], bv[j], acc[i][j]);
        }
        __syncthreads();
    }

    // ---- epilogue: bias (+relu) + store ----
#pragma unroll
    for (int i = 0; i < NPIX; i++) {
        int p = p0 + i;
        int oy, ox, gp;
        bool valid = true;
        if (ONED) {
            int hw = tx * 64 + p;
            valid = hw < OH * OW;
            if (!valid) continue;
            oy = hw / OW;
            ox = hw - oy * OW;
            gp = n * OH * OW + hw;
        } else {
            oy = ty * TPY + (p >> 3);
            ox = tx * TPX + (p & 7);
            gp = n * OH * OW + oy * OW + ox;
        }
#pragma unroll
        for (int j = 0; j < NOC; j++) {
            int oc = oc0 + j;
            float v = acc[i][j] + bias[oc];
            if (RELU) v = fmaxf(v, 0.f);
            if (PIXMAJOR) out[(size_t)gp * OC + oc] = v;
            else          out[((size_t)(n * OC + oc) * OH + oy) * OW + ox] = v;
        }
    }
}

// ---------------------------------------------------------------------------
// VQ: per pixel, argmin over 512 codes of |z|^2 - 2 z.c + |c|^2 (fp32, same
// formula as reference). Grid: 338 pixel-groups x 2 code-halves; each wave
// owns 64 codes, z lives entirely in VGPRs, codebook reads are wave-uniform.
// Winner via packed (monotone-score:idx) u64 atomicMin (lower idx wins ties).
// ---------------------------------------------------------------------------
__global__ __launch_bounds__(256) void vq_kernel(
    const float* __restrict__ z,            // [21632][64]
    const float* __restrict__ cb,           // [512][64]
    unsigned long long* __restrict__ best)  // [21632], preset to ~0
{
    const int tid  = threadIdx.x;
    const int lane = tid & 63;
    const int wv   = tid >> 6;
    const int pg   = blockIdx.x >> 1;
    const int half = blockIdx.x & 1;
    const int p    = pg * 64 + lane;        // 338*64 == 21632 exactly

    __shared__ float c2s[256];
    {
        int code = half * 256 + tid;
        const float* c = cb + (size_t)code * EMB;
        float s = 0.f;
#pragma unroll
        for (int j = 0; j < EMB; j += 4) {
            float4 v = *(const float4*)(c + j);
            s = fmaf(v.x, v.x, s); s = fmaf(v.y, v.y, s);
            s = fmaf(v.z, v.z, s); s = fmaf(v.w, v.w, s);
        }
        c2s[tid] = s;
    }
    __syncthreads();

    float zr[EMB];
    float zz = 0.f;
#pragma unroll
    for (int j = 0; j < EMB; j += 4) {
        float4 v = *(const float4*)(z + (size_t)p * EMB + j);
        zr[j] = v.x; zr[j+1] = v.y; zr[j+2] = v.z; zr[j+3] = v.w;
        zz = fmaf(v.x, v.x, zz); zz = fmaf(v.y, v.y, zz);
        zz = fmaf(v.z, v.z, zz); zz = fmaf(v.w, v.w, zz);
    }

    float bestScore = FLT_MAX;
    int   bestIdx   = 0x7fffffff;
    const int base = half * 256 + wv * 64;
    for (int ci = 0; ci < 64; ci++) {
        int code = __builtin_amdgcn_readfirstlane(base + ci);
        const float* c = cb + (size_t)code * EMB;
        float dot = 0.f;
#pragma unroll
        for (int j = 0; j < EMB; j++) dot = fmaf(zr[j], c[j], dot);
        float score = fmaf(-2.f, dot, zz) + c2s[code - half * 256];
        if (score < bestScore) { bestScore = score; bestIdx = code; }
    }

    unsigned u = __float_as_uint(bestScore);
    u = (bestScore < 0.f) ? ~u : (u | 0x80000000u);
    unsigned long long pk = ((unsigned long long)u << 32) | (unsigned)bestIdx;
    atomicMin(&best[p], pk);
}

__global__ __launch_bounds__(256) void onehot_kernel(
    const unsigned long long* __restrict__ best, float* __restrict__ out)
{
    int p = blockIdx.x * 256 + threadIdx.x;
    if (p >= NPIXT) return;
    int code = (int)(unsigned)(best[p] & 0xffffffffu);
    int b  = p / HW3;
    int hw = p - b * HW3;
    out[((size_t)b * NEMB + code) * HW3 + hw] = 1.0f;
}

extern "C" void kernel_launch(void* const* d_in, const int* in_sizes, int n_in,
                              void* d_out, int out_size, void* d_ws, size_t ws_size,
                              hipStream_t stream) {
    const float* x  = (const float*)d_in[0];
    const float* w1 = (const float*)d_in[1];
    const float* b1 = (const float*)d_in[2];
    const float* w2 = (const float*)d_in[3];
    const float* b2 = (const float*)d_in[4];
    const float* w3 = (const float*)d_in[5];
    const float* b3 = (const float*)d_in[6];
    const float* cb = (const float*)d_in[7];
    float* out = (float*)d_out;

    float* z1 = (float*)d_ws;                                 // 128*64*48*48  = 75.5 MB
    float* z2 = z1 + (size_t)128 * 64 * 48 * 48;              // 128*128*16*16 = 16.8 MB
    float* z3 = z2 + (size_t)128 * 128 * 16 * 16;             // 21632*64      = 5.5 MB
    unsigned long long* best = (unsigned long long*)(z3 + (size_t)NPIXT * EMB);

    hipMemsetAsync(out, 0, (size_t)out_size * sizeof(float), stream);
    hipMemsetAsync(best, 0xFF, (size_t)NPIXT * sizeof(unsigned long long), stream);

    // conv1: 192->48, tiles 6x6 per image
    conv_igemm<3, 64, 8, 8, 192, 192, 48, 48, 4, 2, true,  false, false, 8, 8>
        <<<128 * 36, 256, 0, stream>>>(x, w1, b1, z1);
    // conv2: 48->16, tiles 2x2 per image
    conv_igemm<64, 128, 6, 6, 48, 48, 16, 16, 3, 2, true,  false, false, 8, 8>
        <<<128 * 4, 256, 0, stream>>>(z1, w2, b2, z2);
    // conv3: 16->13, 1D pixel tiling (3 tiles of 64 over 169), pixel-major out
    conv_igemm<128, 64, 4, 4, 16, 16, 13, 13, 1, 0, false, true,  true,  8, 8>
        <<<128 * 3, 256, 0, stream>>>(z2, w3, b3, z3);

    vq_kernel<<<338 * 2, 256, 0, stream>>>(z3, cb, best);
    onehot_kernel<<<(NPIXT + 255) / 256, 256, 0, stream>>>(best, out);
}

// Round 2
// 755.665 us; speedup vs baseline: 1.2311x; 1.2311x over previous
//
#include <hip/hip_runtime.h>
#include <cstdint>
#include <cfloat>

// ---------------------------------------------------------------------------
// SimpleVQVAEEncoder, round 2: "scalar-broadcast" implicit GEMM.
// Each block = 512 threads = 8 waves; tile = 64 pixels (lane==pixel) x OC.
// Wave w owns ocs [w*OC/8, (w+1)*OC/8). B (weights) is wave-uniform ->
// s_load from pre-transposed wt[K][OC] into SGPRs, FMA with SGPR operand.
// A (im2col) staged in LDS once per block, read as conflict-free b32.
// ---------------------------------------------------------------------------

constexpr int B_    = 128;
constexpr int HW3   = 169;
constexpr int NPIXT = B_ * HW3;        // 21632
constexpr int NEMB  = 512;
constexpr int EMB   = 64;

// transpose weights [OC][K] -> [K][OC] (tiny prepass)
__global__ __launch_bounds__(256) void wtrans_kernel(
    const float* __restrict__ w, float* __restrict__ wt, int OC, int K)
{
    int idx = blockIdx.x * 256 + threadIdx.x;
    if (idx >= OC * K) return;
    int oc = idx / K, k = idx - oc * K;
    wt[(size_t)k * OC + oc] = w[idx];
}

template<int IC, int OC, int KH, int KW, int IH, int IW, int OH, int OW,
         int STRIDE, int PAD, bool RELU, bool TRANSOUT>
__global__ __launch_bounds__(512) void conv_sgemm(
    const float* __restrict__ in, const float* __restrict__ wt,   // wt: [K][OC]
    const float* __restrict__ bias, float* __restrict__ out)
{
    constexpr int K   = IC * KH * KW;
    constexpr int BK  = 32;
    constexpr int NOC = OC / 8;        // accs per thread: 8 (OC=64) / 16 (OC=128)
    constexpr int HWo = OH * OW;

    __shared__ float As[BK][64];       // b32 reads: bank = lane%32, 2-way = free

    const int tid  = threadIdx.x;
    const int lane = tid & 63;
    const int wv   = __builtin_amdgcn_readfirstlane(tid >> 6);  // force uniform
    const int oc0  = wv * NOC;
    const int pixbase = blockIdx.x * 64;

    float acc[NOC];
#pragma unroll
    for (int j = 0; j < NOC; j++) acc[j] = 0.f;

    for (int k0 = 0; k0 < K; k0 += BK) {
        __syncthreads();               // previous iter's reads done
#pragma unroll
        for (int i = 0; i < (BK * 64) / 512; i++) {      // 4 elems/thread
            int idx = i * 512 + tid;
            int p  = idx & 63;
            int kk = idx >> 6;
            int k  = k0 + kk;
            int ic = k / (KH * KW);
            int r  = k - ic * (KH * KW);
            int ky = r / KW;
            int kx = r - ky * KW;
            int pix = pixbase + p;
            int n  = pix / HWo;
            int hw = pix - n * HWo;
            int oy = hw / OW;
            int ox = hw - oy * OW;
            int iy = oy * STRIDE - PAD + ky;
            int ix = ox * STRIDE - PAD + kx;
            float v = 0.f;
            if (iy >= 0 && iy < IH && ix >= 0 && ix < IW)
                v = in[((size_t)(n * IC + ic) * IH + iy) * IW + ix];
            As[kk][p] = v;
        }
        __syncthreads();

        const float* bp = wt + (size_t)k0 * OC + oc0;    // wave-uniform address
#pragma unroll
        for (int kk = 0; kk < BK; kk++) {
            float a = As[kk][lane];
#pragma unroll
            for (int j = 0; j < NOC; j++)
                acc[j] = fmaf(a, bp[kk * OC + j], acc[j]);   // s_load + v_fmac(s,v)
        }
    }

    // epilogue: bias (+relu), store
    int pix = pixbase + lane;
    int n   = pix / HWo;
    int hw  = pix - n * HWo;
#pragma unroll
    for (int j = 0; j < NOC; j++) {
        int oc  = oc0 + j;
        float v = acc[j] + bias[oc];
        if (RELU) v = fmaxf(v, 0.f);
        if (TRANSOUT) out[(size_t)oc * NPIXT + pix] = v;                 // z3t[oc][pix]
        else          out[((size_t)(n * OC + oc)) * HWo + hw] = v;       // NCHW
    }
}

// ---------------------------------------------------------------------------
// VQ: per pixel argmin over 512 codes of |z|^2 - 2 z.c + |c|^2.
// z now transposed [64][21632] -> coalesced loads. Codebook reads wave-uniform.
// ---------------------------------------------------------------------------
__global__ __launch_bounds__(256) void vq_kernel(
    const float* __restrict__ zt,           // [64][21632]
    const float* __restrict__ cb,           // [512][64]
    unsigned long long* __restrict__ best)  // [21632], preset to ~0
{
    const int tid  = threadIdx.x;
    const int lane = tid & 63;
    const int wv   = tid >> 6;
    const int pg   = blockIdx.x >> 1;
    const int half = blockIdx.x & 1;
    const int p    = pg * 64 + lane;        // 338*64 == 21632 exactly

    __shared__ float c2s[256];
    {
        int code = half * 256 + tid;
        const float* c = cb + (size_t)code * EMB;
        float s = 0.f;
#pragma unroll
        for (int j = 0; j < EMB; j += 4) {
            float4 v = *(const float4*)(c + j);
            s = fmaf(v.x, v.x, s); s = fmaf(v.y, v.y, s);
            s = fmaf(v.z, v.z, s); s = fmaf(v.w, v.w, s);
        }
        c2s[tid] = s;
    }
    __syncthreads();

    float zr[EMB];
    float zz = 0.f;
#pragma unroll
    for (int j = 0; j < EMB; j++) {
        float v = zt[(size_t)j * NPIXT + p];
        zr[j] = v;
        zz = fmaf(v, v, zz);
    }

    float bestScore = FLT_MAX;
    int   bestIdx   = 0x7fffffff;
    const int base = half * 256 + wv * 64;
    for (int ci = 0; ci < 64; ci++) {
        int code = __builtin_amdgcn_readfirstlane(base + ci);
        const float* c = cb + (size_t)code * EMB;
        float dot = 0.f;
#pragma unroll
        for (int j = 0; j < EMB; j++) dot = fmaf(zr[j], c[j], dot);
        float score = fmaf(-2.f, dot, zz) + c2s[code - half * 256];
        if (score < bestScore) { bestScore = score; bestIdx = code; }
    }

    unsigned u = __float_as_uint(bestScore);
    u = (bestScore < 0.f) ? ~u : (u | 0x80000000u);
    unsigned long long pk = ((unsigned long long)u << 32) | (unsigned)bestIdx;
    atomicMin(&best[p], pk);
}

__global__ __launch_bounds__(256) void onehot_kernel(
    const unsigned long long* __restrict__ best, float* __restrict__ out)
{
    int p = blockIdx.x * 256 + threadIdx.x;
    if (p >= NPIXT) return;
    int code = (int)(unsigned)(best[p] & 0xffffffffu);
    int b  = p / HW3;
    int hw = p - b * HW3;
    out[((size_t)b * NEMB + code) * HW3 + hw] = 1.0f;
}

extern "C" void kernel_launch(void* const* d_in, const int* in_sizes, int n_in,
                              void* d_out, int out_size, void* d_ws, size_t ws_size,
                              hipStream_t stream) {
    const float* x  = (const float*)d_in[0];
    const float* w1 = (const float*)d_in[1];
    const float* b1 = (const float*)d_in[2];
    const float* w2 = (const float*)d_in[3];
    const float* b2 = (const float*)d_in[4];
    const float* w3 = (const float*)d_in[5];
    const float* b3 = (const float*)d_in[6];
    const float* cb = (const float*)d_in[7];
    float* out = (float*)d_out;

    float* z1  = (float*)d_ws;                            // 128*64*48*48   = 75.5 MB
    float* z2  = z1 + (size_t)128 * 64 * 48 * 48;         // 128*128*16*16  = 16.8 MB
    float* z3t = z2 + (size_t)128 * 128 * 16 * 16;        // [64][21632]    =  5.5 MB
    unsigned long long* best = (unsigned long long*)(z3t + (size_t)EMB * NPIXT);
    float* w1t = (float*)(best + NPIXT);                  // [192][64]
    float* w2t = w1t + 192 * 64;                          // [2304][128]
    float* w3t = w2t + 2304 * 128;                        // [2048][64]

    hipMemsetAsync(out, 0, (size_t)out_size * sizeof(float), stream);
    hipMemsetAsync(best, 0xFF, (size_t)NPIXT * sizeof(unsigned long long), stream);

    wtrans_kernel<<<(64 * 192 + 255) / 256, 256, 0, stream>>>(w1, w1t, 64, 192);
    wtrans_kernel<<<(128 * 2304 + 255) / 256, 256, 0, stream>>>(w2, w2t, 128, 2304);
    wtrans_kernel<<<(64 * 2048 + 255) / 256, 256, 0, stream>>>(w3, w3t, 64, 2048);

    // conv1: M = 128*48*48 = 294912 pixels -> 4608 blocks
    conv_sgemm<3, 64, 8, 8, 192, 192, 48, 48, 4, 2, true, false>
        <<<294912 / 64, 512, 0, stream>>>(x, w1t, b1, z1);
    // conv2: M = 128*16*16 = 32768 pixels -> 512 blocks
    conv_sgemm<64, 128, 6, 6, 48, 48, 16, 16, 3, 2, true, false>
        <<<32768 / 64, 512, 0, stream>>>(z1, w2t, b2, z2);
    // conv3: M = 128*169 = 21632 pixels -> 338 blocks, transposed output
    conv_sgemm<128, 64, 4, 4, 16, 16, 13, 13, 1, 0, false, true>
        <<<NPIXT / 64, 512, 0, stream>>>(z2, w3t, b3, z3t);

    vq_kernel<<<338 * 2, 256, 0, stream>>>(z3t, cb, best);
    onehot_kernel<<<(NPIXT + 255) / 256, 256, 0, stream>>>(best, out);
}